// Round 11
// baseline (151.223 us; speedup 1.0000x reference)
//
#include <hip/hip_runtime.h>
#include <hip/hip_bf16.h>
#include <math.h>

#define BB 4
#define NN 512
#define TT 24
#define NXF 8
#define HH 64
#define PRED 12
#define MM (BB*NN)   // 2048

typedef __attribute__((ext_vector_type(8))) short short8;
typedef __attribute__((ext_vector_type(4))) float f32x4;
typedef unsigned short ushort;

// ---- workspace layout (float offsets) ----
// Each transposed plane: BB*HH*NN = 131072 bf16 = 65536 f32 slots  (R8-R10 bug: was 32768)
#define WS_H1THI   0         // [0,      65536)
#define WS_H1TLO   65536     // [65536, 131072)
#define WS_H2THI   131072    // [131072,196608)
#define WS_H2TLO   196608    // [196608,262144)
#define WS_HL      262144    // [262144,393216)  f32
#define WS_EL      393216    // 2048
#define WS_ER      395264
#define WS_EL2     397312
#define WS_ER2     399360
#define WS_WCOMB   401408    // 2048
#define WS_BCOMB   403456    // 256
#define WS_WHHFRAG 403712    // 16384 ushort = 8192 f32 -> ends 411904 (~1.65 MB)

#define LHS 72
#define LXS 40

__device__ inline float sigm(float x){ return 1.f/(1.f+__expf(-x)); }
__device__ inline float tanh_fast(float x){ float e=__expf(2.f*x); return 1.f - 2.f/(e+1.f); }
__device__ inline float gelu_exact(float x){ return 0.5f*x*(1.f+erff(x*0.70710678118654752440f)); }
__device__ inline ushort f2bu(float f){           // RNE f32 -> bf16 bits
    unsigned b=__float_as_uint(f);
    return (ushort)((b + 0x7FFFu + ((b>>16)&1u))>>16);
}
__device__ inline float bu2f(ushort u){ return __uint_as_float(((unsigned)u)<<16); }

__device__ inline void split8(const float* f, short8& hi, short8& lo){
    #pragma unroll
    for (int j = 0; j < 8; ++j){
        ushort h = f2bu(f[j]);
        hi[j] = (short)h;
        lo[j] = (short)f2bu(f[j] - bu2f(h));
    }
}

// =============== K1: gat1pre -> H1T bf16 planes ; el1, er1 (+ LSTM precomp blocks) ===============
__global__ __launch_bounds__(256,2) void gat1pre_kernel(
    const float* __restrict__ x, const float* __restrict__ Wfc, const float* __restrict__ bfc,
    const float* __restrict__ W1, const float* __restrict__ al1, const float* __restrict__ ar1,
    const float* __restrict__ Wih, const float* __restrict__ Whh,
    const float* __restrict__ bih, const float* __restrict__ bhh,
    ushort* __restrict__ H1Thi, ushort* __restrict__ H1Tlo,
    float* __restrict__ el, float* __restrict__ er,
    float* __restrict__ wcombG, float* __restrict__ bcombG,
    ushort* __restrict__ whhfrag)
{
    __shared__ float sw1[HH*HH];
    __shared__ float swfc[NXF*HH];
    __shared__ float sb[HH], sal[HH], sar[HH];
    __shared__ float sxh[4][68];
    __shared__ float sx[4][NXF];
    const int t = threadIdx.x;

    if (blockIdx.x >= 512){
        const int f = blockIdx.x - 512;   // 0..7
        const int ng = t;
        float accf = 0.f, accb = 0.f;
        const float* wr = Wih + ng*64;
        #pragma unroll
        for (int k = 0; k < 64; ++k){
            float wv = wr[k];
            accf += Wfc[f*64 + k] * wv;
            accb += bfc[k] * wv;
        }
        wcombG[f*256 + ng] = accf;
        if (f == 0) bcombG[ng] = accb + bih[ng] + bhh[ng];
        #pragma unroll
        for (int u = 0; u < 8; ++u){
            int o = f*2048 + u*256 + t;
            int F  = o >> 9;
            int ln = (o >> 3) & 63;
            int j  = o & 7;
            int w_ = F >> 3, tt = (F >> 1) & 3, ks = F & 1;
            int q = ln >> 4, c = ln & 15;
            int ngx = (w_ + 4*tt)*16 + c;
            whhfrag[o] = f2bu(Whh[ngx*64 + ks*32 + q*8 + j]);
        }
        return;
    }

    const int r = t >> 6, h = t & 63;
    #pragma unroll
    for (int i = 0; i < 16; ++i) sw1[t + 256*i] = W1[t + 256*i];
    swfc[t] = Wfc[t];
    swfc[t+256] = Wfc[t+256];
    if (t < 64) sb[t] = bfc[t];
    else if (t < 128) sal[t-64] = al1[t-64];
    else if (t < 192) sar[t-128] = ar1[t-128];
    if (t < 32){
        int rr = t >> 3, f = t & 7;
        sx[rr][f] = x[(size_t)(blockIdx.x*4 + rr)*(TT*NXF) + (TT-1)*NXF + f];
    }
    __syncthreads();
    float xh = sb[h];
    #pragma unroll
    for (int f = 0; f < NXF; ++f) xh += sx[r][f]*swfc[f*HH + h];
    sxh[r][h] = xh;
    __syncthreads();
    float acc = 0.f;
    const float4* xr = (const float4*)&sxh[r][0];
    #pragma unroll
    for (int k4 = 0; k4 < 16; ++k4){
        float4 xv = xr[k4];
        acc += xv.x*sw1[(4*k4+0)*HH+h] + xv.y*sw1[(4*k4+1)*HH+h]
             + xv.z*sw1[(4*k4+2)*HH+h] + xv.w*sw1[(4*k4+3)*HH+h];
    }
    const int m = blockIdx.x*4 + r;
    {
        int bb = m >> 9, ml = m & 511;
        ushort hu = f2bu(acc);
        H1Thi[((size_t)(bb*HH + h))*NN + ml] = hu;
        H1Tlo[((size_t)(bb*HH + h))*NN + ml] = f2bu(acc - bu2f(hu));
    }
    float v1 = acc*sal[h], v2 = acc*sar[h];
    #pragma unroll
    for (int o = 32; o; o >>= 1){ v1 += __shfl_xor(v1,o); v2 += __shfl_xor(v2,o); }
    if (h == 0){ el[m] = v1; er[m] = v2; }
}

// =============== K2: blocks 0-127 = attn1 + GAT2-pre ; blocks 128-255 = LSTM -> hl ===============
__global__ __launch_bounds__(256,2) void mid_fused_kernel(
    const ushort* __restrict__ H1Thi, const ushort* __restrict__ H1Tlo,
    const float* __restrict__ el_in, const float* __restrict__ er_in,
    const int* __restrict__ ei, int E,
    const float* __restrict__ bias1,
    const float* __restrict__ W2, const float* __restrict__ al2, const float* __restrict__ ar2,
    ushort* __restrict__ H2Thi, ushort* __restrict__ H2Tlo,
    float* __restrict__ el2, float* __restrict__ er2,
    const float* __restrict__ x,
    const float* __restrict__ wcombG, const float* __restrict__ bcombG,
    const ushort* __restrict__ whhfrag,
    float* __restrict__ hl)
{
    __shared__ __align__(16) char smem[58880];
    const int t = threadIdx.x;
    const int lane = t & 63;
    const int w = t >> 6;
    const int quad = lane >> 4;
    const int c16 = lane & 15;

    if (blockIdx.x >= 128){
        // ---------------- LSTM branch (verbatim R7-passing) ----------------
        ushort* hbi = (ushort*)smem;            // [2][16*LHS]
        ushort* hlo = (ushort*)(smem + 4608);
        ushort* xls = (ushort*)(smem + 9216);   // [TT*16*LXS]
        const int m0 = (blockIdx.x - 128) * 16;

        {
            unsigned* h0 = (unsigned*)hbi;
            unsigned* l0 = (unsigned*)hlo;
            for (int i = t; i < 2*16*LHS/2; i += 256){ h0[i] = 0u; l0[i] = 0u; }
            unsigned* xw = (unsigned*)xls;
            for (int i = t; i < TT*16*LXS/2; i += 256) xw[i] = 0u;
        }
        short8 bw[4][2]; short8 bx[4]; float bc[4];
        #pragma unroll
        for (int tt = 0; tt < 4; ++tt){
            const int ng = (w + 4*tt)*16 + c16;
            bc[tt] = bcombG[ng];
            #pragma unroll
            for (int ks = 0; ks < 2; ++ks)
                bw[tt][ks] = *(const short8*)&whhfrag[(((w*4+tt)*2)+ks)*512 + lane*8];
            short8 vx = {0,0,0,0,0,0,0,0};
            if (quad == 0){
                #pragma unroll
                for (int j = 0; j < 8; ++j) vx[j] = (short)f2bu(wcombG[j*256 + ng]);
            }
            bx[tt] = vx;
        }
        __syncthreads();
        for (int i = t; i < 16*TT*NXF; i += 256){
            int r = i / (TT*NXF);
            int rem = i - r*(TT*NXF);
            int st = rem >> 3, f = rem & 7;
            xls[st*(16*LXS) + r*LXS + f] = f2bu(x[(size_t)(m0+r)*(TT*NXF) + rem]);
        }
        __syncthreads();

        float cst[4] = {0,0,0,0};
        float hf[4]  = {0,0,0,0};

        for (int st = 0; st < TT; ++st){
            const int p = st & 1;
            const ushort* hb  = hbi + p*(16*LHS);
            const ushort* hl_ = hlo + p*(16*LHS);
            short8 ahi0 = *(const short8*)&hb[c16*LHS + quad*8];
            short8 ahi1 = *(const short8*)&hb[c16*LHS + 32 + quad*8];
            short8 alo0 = *(const short8*)&hl_[c16*LHS + quad*8];
            short8 alo1 = *(const short8*)&hl_[c16*LHS + 32 + quad*8];
            short8 ax   = *(const short8*)&xls[st*(16*LXS) + c16*LXS + quad*8];
            f32x4 acc[4];
            #pragma unroll
            for (int tt = 0; tt < 4; ++tt){
                f32x4 a = {bc[tt], bc[tt], bc[tt], bc[tt]};
                a = __builtin_amdgcn_mfma_f32_16x16x32_bf16(ax,   bx[tt],    a, 0,0,0);
                a = __builtin_amdgcn_mfma_f32_16x16x32_bf16(ahi0, bw[tt][0], a, 0,0,0);
                a = __builtin_amdgcn_mfma_f32_16x16x32_bf16(ahi1, bw[tt][1], a, 0,0,0);
                a = __builtin_amdgcn_mfma_f32_16x16x32_bf16(alo0, bw[tt][0], a, 0,0,0);
                a = __builtin_amdgcn_mfma_f32_16x16x32_bf16(alo1, bw[tt][1], a, 0,0,0);
                acc[tt] = a;
            }
            ushort* ho   = hbi + (p^1)*(16*LHS);
            ushort* lo_o = hlo + (p^1)*(16*LHS);
            #pragma unroll
            for (int reg = 0; reg < 4; ++reg){
                float gi = acc[0][reg], gf = acc[1][reg], gg = acc[2][reg], go = acc[3][reg];
                float cn = sigm(gf)*cst[reg] + sigm(gi)*tanh_fast(gg);
                cst[reg] = cn;
                float hn = sigm(go)*tanh_fast(cn);
                hf[reg] = hn;
                ushort hu = f2bu(hn);
                float lov = hn - bu2f(hu);
                int addr = (quad*4+reg)*LHS + w*16 + c16;
                ho[addr] = hu;
                lo_o[addr] = f2bu(lov);
            }
            __syncthreads();
        }
        #pragma unroll
        for (int reg = 0; reg < 4; ++reg)
            hl[(size_t)(m0 + quad*4 + reg)*HH + w*16 + c16] = hf[reg];
        return;
    }

    // ---------------- attn layer1 + GAT2-pre branch ----------------
    unsigned (*smask)[16] = (unsigned(*)[16])smem;                 // 1024
    float* er_s  = (float*)(smem + 1024);                          // 2048
    float* sal   = (float*)(smem + 3072);                          // 256
    float* sar   = (float*)(smem + 3328);                          // 256
    float (*alpha)[516] = (float(*)[516])(smem + 3584);            // 33024 -> 36608
    float* uSpace = (float*)(smem + 36608);                        // 17920 (sw2)
    float (*xh2)[68] = (float(*)[68])(smem + 54528);               // 4352 -> 58880

    const int b = blockIdx.x >> 5;
    const int m0 = (blockIdx.x & 31) * 16;
    const int l = lane;

    if (t < 64) sal[t] = al2[t]; else if (t < 128) sar[t-64] = ar2[t-64];
    ((unsigned*)smask)[t] = 0;
    er_s[t] = er_in[b*NN + t];
    er_s[t+256] = er_in[b*NN + t + 256];
    __syncthreads();
    for (int e = t; e < E; e += 256){
        int s = ei[e];
        unsigned rl = (unsigned)(s - m0);
        if (rl < 16u){
            int d = ei[E + e];
            atomicOr(&smask[rl][d>>5], 1u << (d & 31));
        }
    }
    __syncthreads();
    // phase A: masked softmax -> alpha (f32, padded rows)
    for (int q = 0; q < 4; ++q){
        const int i = w*4 + q;
        const float elv = el_in[b*NN + m0 + i];
        float e8[8]; unsigned mk = 0; float mx = -1e30f;
        #pragma unroll
        for (int j = 0; j < 8; ++j){
            int n = l + 64*j;
            float ev = elv + er_s[n];
            ev = ev >= 0.f ? ev : 0.2f*ev;
            unsigned mb = (smask[i][(l>>5) + 2*j] >> (l & 31)) & 1u;
            e8[j] = ev;
            if (mb){ mk |= (1u<<j); mx = fmaxf(mx, ev); }
        }
        #pragma unroll
        for (int o = 32; o; o >>= 1) mx = fmaxf(mx, __shfl_xor(mx, o));
        float s = 0.f;
        #pragma unroll
        for (int j = 0; j < 8; ++j){
            float p = ((mk>>j) & 1u) ? __expf(e8[j]-mx) : 0.f;
            e8[j] = p; s += p;
        }
        #pragma unroll
        for (int o = 32; o; o >>= 1) s += __shfl_xor(s, o);
        const float inv = 1.f/s;
        #pragma unroll
        for (int j = 0; j < 8; ++j) alpha[i][l + 64*j] = e8[j]*inv;
    }
    __syncthreads();

    // phase B: barrier-free MFMA; A from f32 alpha (split at read), B from global bf16 planes
    const ushort* bhp = H1Thi + ((size_t)(b*HH + w*16 + c16))*NN;
    const ushort* blp = H1Tlo + ((size_t)(b*HH + w*16 + c16))*NN;
    f32x4 acc = {0.f,0.f,0.f,0.f};
    for (int k0 = 0; k0 < NN; k0 += 32){
        const float* ap = &alpha[c16][k0 + quad*8];
        float4 a0 = *(const float4*)ap;
        float4 a1 = *(const float4*)(ap + 4);
        float af[8] = {a0.x,a0.y,a0.z,a0.w,a1.x,a1.y,a1.z,a1.w};
        short8 a_h, a_l;
        split8(af, a_h, a_l);
        short8 b_h = *(const short8*)&bhp[k0 + quad*8];
        short8 b_l = *(const short8*)&blp[k0 + quad*8];
        acc = __builtin_amdgcn_mfma_f32_16x16x32_bf16(a_h, b_h, acc, 0,0,0);
        acc = __builtin_amdgcn_mfma_f32_16x16x32_bf16(a_l, b_h, acc, 0,0,0);
        acc = __builtin_amdgcn_mfma_f32_16x16x32_bf16(a_h, b_l, acc, 0,0,0);
    }
    __syncthreads();   // alpha dead
    {
        const int h = w*16 + c16;
        const float bv = bias1[h];
        #pragma unroll
        for (int reg = 0; reg < 4; ++reg)
            xh2[quad*4 + reg][h] = gelu_exact(acc[reg] + bv);
    }
    float* sw2 = uSpace;
    #pragma unroll
    for (int i = 0; i < 16; ++i) sw2[t + 256*i] = W2[t + 256*i];
    __syncthreads();
    // fused GAT2 pre -> H2T planes ; el2, er2
    {
        const int h = l;
        for (int q = 0; q < 4; ++q){
            const int i = w + 4*q;
            float acc2 = 0.f;
            const float4* xr = (const float4*)&xh2[i][0];
            #pragma unroll
            for (int k4 = 0; k4 < 16; ++k4){
                float4 xv = xr[k4];
                acc2 += xv.x*sw2[(4*k4+0)*HH+h] + xv.y*sw2[(4*k4+1)*HH+h]
                      + xv.z*sw2[(4*k4+2)*HH+h] + xv.w*sw2[(4*k4+3)*HH+h];
            }
            const int m = b*NN + m0 + i;
            ushort hu = f2bu(acc2);
            H2Thi[((size_t)(b*HH + h))*NN + (m0 + i)] = hu;
            H2Tlo[((size_t)(b*HH + h))*NN + (m0 + i)] = f2bu(acc2 - bu2f(hu));
            float v1 = acc2*sal[h], v2 = acc2*sar[h];
            #pragma unroll
            for (int o = 32; o; o >>= 1){ v1 += __shfl_xor(v1,o); v2 += __shfl_xor(v2,o); }
            if (h == 0){ el2[m] = v1; er2[m] = v2; }
        }
    }
}

// =============== K3: attn layer2 + LN(g2)+LN(hl) + decode ===============
__global__ __launch_bounds__(256,2) void attn2_final_kernel(
    const ushort* __restrict__ H2Thi, const ushort* __restrict__ H2Tlo,
    const float* __restrict__ el_in, const float* __restrict__ er_in,
    const int* __restrict__ ei, int E,
    const float* __restrict__ bias2,
    const float* __restrict__ hl,
    const float* __restrict__ g_l, const float* __restrict__ b_l,
    const float* __restrict__ g_g, const float* __restrict__ b_g,
    const float* __restrict__ W_d, const float* __restrict__ b_d,
    float* __restrict__ out)
{
    __shared__ __align__(16) char smem[54016];
    unsigned (*smask)[16] = (unsigned(*)[16])smem;                 // 1024
    float* er_s  = (float*)(smem + 1024);                          // 2048
    float (*alpha)[516] = (float(*)[516])(smem + 3072);            // 33024 -> 36096
    // sdec region at 36096

    const int t = threadIdx.x;
    const int b = blockIdx.x >> 5;
    const int m0 = (blockIdx.x & 31) * 16;
    const int l = t & 63, w = t >> 6;
    const int quad = l >> 4, c16 = l & 15;

    ((unsigned*)smask)[t] = 0;
    er_s[t] = er_in[b*NN + t];
    er_s[t+256] = er_in[b*NN + t + 256];
    __syncthreads();
    for (int e = t; e < E; e += 256){
        int s = ei[e];
        unsigned rl = (unsigned)(s - m0);
        if (rl < 16u){
            int d = ei[E + e];
            atomicOr(&smask[rl][d>>5], 1u << (d & 31));
        }
    }
    __syncthreads();
    for (int q = 0; q < 4; ++q){
        const int i = w*4 + q;
        const float elv = el_in[b*NN + m0 + i];
        float e8[8]; unsigned mk = 0; float mx = -1e30f;
        #pragma unroll
        for (int j = 0; j < 8; ++j){
            int n = l + 64*j;
            float ev = elv + er_s[n];
            ev = ev >= 0.f ? ev : 0.2f*ev;
            unsigned mb = (smask[i][(l>>5) + 2*j] >> (l & 31)) & 1u;
            e8[j] = ev;
            if (mb){ mk |= (1u<<j); mx = fmaxf(mx, ev); }
        }
        #pragma unroll
        for (int o = 32; o; o >>= 1) mx = fmaxf(mx, __shfl_xor(mx, o));
        float s = 0.f;
        #pragma unroll
        for (int j = 0; j < 8; ++j){
            float p = ((mk>>j) & 1u) ? __expf(e8[j]-mx) : 0.f;
            e8[j] = p; s += p;
        }
        #pragma unroll
        for (int o = 32; o; o >>= 1) s += __shfl_xor(s, o);
        const float inv = 1.f/s;
        #pragma unroll
        for (int j = 0; j < 8; ++j) alpha[i][l + 64*j] = e8[j]*inv;
    }
    __syncthreads();

    const ushort* bhp = H2Thi + ((size_t)(b*HH + w*16 + c16))*NN;
    const ushort* blp = H2Tlo + ((size_t)(b*HH + w*16 + c16))*NN;
    f32x4 acc = {0.f,0.f,0.f,0.f};
    for (int k0 = 0; k0 < NN; k0 += 32){
        const float* ap = &alpha[c16][k0 + quad*8];
        float4 a0 = *(const float4*)ap;
        float4 a1 = *(const float4*)(ap + 4);
        float af[8] = {a0.x,a0.y,a0.z,a0.w,a1.x,a1.y,a1.z,a1.w};
        short8 a_h, a_l;
        split8(af, a_h, a_l);
        short8 b_h = *(const short8*)&bhp[k0 + quad*8];
        short8 b_l = *(const short8*)&blp[k0 + quad*8];
        acc = __builtin_amdgcn_mfma_f32_16x16x32_bf16(a_h, b_h, acc, 0,0,0);
        acc = __builtin_amdgcn_mfma_f32_16x16x32_bf16(a_l, b_h, acc, 0,0,0);
        acc = __builtin_amdgcn_mfma_f32_16x16x32_bf16(a_h, b_l, acc, 0,0,0);
    }
    __syncthreads();   // alpha dead
    float* sg2  = (float*)(smem + 3072);
    float* sdec = (float*)(smem + 36096);
    {
        const int h = w*16 + c16;
        const float bv = bias2[h];
        #pragma unroll
        for (int reg = 0; reg < 4; ++reg)
            sg2[(quad*4 + reg)*HH + h] = gelu_exact(acc[reg] + bv);
    }
    __syncthreads();
    const int gbase = b*NN + m0;
    {
        const int h = l;
        for (int q = 0; q < 4; ++q){
            const int ml = w*4 + q;
            float gv = sg2[ml*HH + h];
            float lv = hl[(size_t)(gbase + ml)*HH + h];

            float s1 = gv;
            #pragma unroll
            for (int o = 32; o; o >>= 1) s1 += __shfl_xor(s1, o);
            float dg = gv - s1*(1.f/64.f);
            float v1 = dg*dg;
            #pragma unroll
            for (int o = 32; o; o >>= 1) v1 += __shfl_xor(v1, o);
            float lng = dg*rsqrtf(v1*(1.f/64.f) + 1e-5f)*g_g[h] + b_g[h];

            float s2 = lv;
            #pragma unroll
            for (int o = 32; o; o >>= 1) s2 += __shfl_xor(s2, o);
            float dl = lv - s2*(1.f/64.f);
            float v2 = dl*dl;
            #pragma unroll
            for (int o = 32; o; o >>= 1) v2 += __shfl_xor(v2, o);
            float lnl = dl*rsqrtf(v2*(1.f/64.f) + 1e-5f)*g_l[h] + b_l[h];

            sdec[ml*HH + h] = lng + lnl;
        }
    }
    __syncthreads();
    if (t < 16*PRED){
        int rr = t / PRED, pp = t - rr*PRED;
        float a = b_d[pp];
        #pragma unroll
        for (int k = 0; k < HH; ++k) a += sdec[rr*HH + k]*W_d[k*PRED + pp];
        out[(size_t)(gbase + rr)*PRED + pp] = a;
    }
}

extern "C" void kernel_launch(void* const* d_in, const int* in_sizes, int n_in,
                              void* d_out, int out_size, void* d_ws, size_t ws_size,
                              hipStream_t stream){
    const float* x    = (const float*)d_in[0];
    const int*   ei   = (const int*)  d_in[1];
    const float* Wfc  = (const float*)d_in[2];
    const float* bfc  = (const float*)d_in[3];
    const float* W1   = (const float*)d_in[4];
    const float* al1  = (const float*)d_in[5];
    const float* ar1  = (const float*)d_in[6];
    const float* bias1= (const float*)d_in[7];
    const float* W2   = (const float*)d_in[8];
    const float* al2  = (const float*)d_in[9];
    const float* ar2  = (const float*)d_in[10];
    const float* bias2= (const float*)d_in[11];
    const float* Wih  = (const float*)d_in[12];
    const float* Whh  = (const float*)d_in[13];
    const float* bih  = (const float*)d_in[14];
    const float* bhh  = (const float*)d_in[15];
    const float* g_l  = (const float*)d_in[16];
    const float* b_l  = (const float*)d_in[17];
    const float* g_g  = (const float*)d_in[18];
    const float* b_g  = (const float*)d_in[19];
    const float* W_d  = (const float*)d_in[20];
    const float* b_d  = (const float*)d_in[21];

    float* ws = (float*)d_ws;
    const int E = in_sizes[1] / 2;

    gat1pre_kernel<<<512 + 8, 256, 0, stream>>>(x, Wfc, bfc, W1, al1, ar1,
                                                Wih, Whh, bih, bhh,
                                                (ushort*)(ws+WS_H1THI), (ushort*)(ws+WS_H1TLO),
                                                ws+WS_EL, ws+WS_ER,
                                                ws+WS_WCOMB, ws+WS_BCOMB,
                                                (ushort*)(ws+WS_WHHFRAG));
    mid_fused_kernel<<<256, 256, 0, stream>>>((const ushort*)(ws+WS_H1THI), (const ushort*)(ws+WS_H1TLO),
                                              ws+WS_EL, ws+WS_ER,
                                              ei, E, bias1, W2, al2, ar2,
                                              (ushort*)(ws+WS_H2THI), (ushort*)(ws+WS_H2TLO),
                                              ws+WS_EL2, ws+WS_ER2,
                                              x, ws+WS_WCOMB, ws+WS_BCOMB,
                                              (const ushort*)(ws+WS_WHHFRAG),
                                              ws+WS_HL);
    attn2_final_kernel<<<BB*(NN/16), 256, 0, stream>>>((const ushort*)(ws+WS_H2THI), (const ushort*)(ws+WS_H2TLO),
                                                       ws+WS_EL2, ws+WS_ER2,
                                                       ei, E, bias2,
                                                       ws+WS_HL,
                                                       g_l, b_l, g_g, b_g, W_d, b_d,
                                                       (float*)d_out);
}